// Round 7
// baseline (45.676 us; speedup 1.0000x reference)
//
#include <hip/hip_runtime.h>
#include <math.h>

// Problem constants (match reference)
#define BB 64
#define HH 224
#define WW 224
#define CC 3

constexpr float FACTOR  = 0.2f;
constexpr float SCALE_K = 1.0f / 255.0f;
constexpr float TWO_PI_F = 6.283185307179586f;
constexpr float CX = (WW - 1) * 0.5f;            // 111.5
constexpr float CY = (HH - 1) * 0.5f;            // 111.5
constexpr int PIX = HH * WW;                     // 50176
constexpr int IMG_ELEMS = PIX * CC;              // 150528

constexpr int TILES_X = WW / 16;                 // 14
constexpr int TILES_PER_IMG = TILES_X * TILES_X; // 196
constexpr int NXCD = 8;
constexpr int NBLOCKS = BB * TILES_PER_IMG;      // 12544

typedef float f32x4 __attribute__((ext_vector_type(4), aligned(4)));

// Valid for i in [-n, 2n-1] — true for every coordinate in this pipeline
// (worst raw coords: translate |K|<=45 -> [-45,268]; zoom grid [-23,268];
// rotate taps [-48,270]; all within [-224,447]).
__device__ __forceinline__ int reflect1(int i, int n) {
    i = (i < 0) ? (-1 - i) : i;
    return (i >= n) ? (2 * n - 1 - i) : i;
}

// Hull [lo,hi] of reflect1 over the integer range [a,b] (piecewise-V: extremes
// are the endpoints plus the fold apexes at {-1,0} (->0) and {n-1,n} (->n-1)).
__device__ __forceinline__ void rhull(int a, int b, int n, int& lo, int& hi) {
    int ra = reflect1(a, n), rb = reflect1(b, n);
    lo = min(ra, rb); hi = max(ra, rb);
    if (a <= 0 && b >= -1) lo = 0;
    if (b >= n - 1 && a <= n) hi = n - 1;
}

// block i -> XCD i%8 (HW round-robin); batch b pinned to XCD b%8 so all
// tiles of an image share one L2 (602KB fp32/image; 8 images/XCD).
__device__ __forceinline__ void decode_tile(int bid, int& b, int& tx, int& ty) {
    int xcd  = bid & (NXCD - 1);
    int slot = bid >> 3;
    int bi   = slot / TILES_PER_IMG;
    int t    = slot - bi * TILES_PER_IMG;
    b = xcd + bi * NXCD;
    ty = t / TILES_X;
    tx = t - ty * TILES_X;
}

// Fully fused rescale+rotate+zoom+translate+flip for one 16x16 output tile.
// Chain of exact per-stage FP trees (same expressions as the passing R4-R6
// kernels), all intermediates fp32 in LDS:
//   stage: 32x32 original px window (pre-scaled; window >= reflected hull of
//          the rotated bbox of the zoom tap grid — fits by 21*sqrt(2)+2<32)
//   G:     rotate-stage values on the zoom tap grid [Gx0..Gx1]x[Gy0..Gy1]
//   Z:     zoom-stage values on the 17x17 translate window
//   out:   translate blend with batch-uniform weights, flip folded in.
__global__ __launch_bounds__(256)
void fused_kernel(const float* __restrict__ image, float* __restrict__ out,
                  const float* __restrict__ angle_u,
                  const float* __restrict__ zoom_u,
                  const float* __restrict__ shift_u,
                  const float* __restrict__ flip_u) {
    __shared__ float SS[32 * 100];      // 32 rows x 32px x 3ch, pitch 100 dw
    __shared__ float G[484 * 3];        // 22x22 grid, pitch 22, packed RGB
    __shared__ float Z[289 * 3];        // 17x17

    int b, tx, ty;
    decode_tile(blockIdx.x, b, tx, ty);
    const int ox = tx * 16, oy = ty * 16;

    // --- per-batch params (exact reference expressions) ---
    const float theta = (2.0f * angle_u[b] - 1.0f) * FACTOR * TWO_PI_F;
    const float c = __cosf(theta), s = __sinf(theta);
    const float zh = 1.0f + (2.0f * zoom_u[2 * b + 0] - 1.0f) * FACTOR;
    const float zw = 1.0f + (2.0f * zoom_u[2 * b + 1] - 1.0f) * FACTOR;
    const float dy = ((2.0f * shift_u[2 * b + 0] - 1.0f) * FACTOR) * (float)HH;
    const float dx = ((2.0f * shift_u[2 * b + 1] - 1.0f) * FACTOR) * (float)WW;
    const bool flip = flip_u[b] > 0.5f;

    const float ndxf = floorf(-dx), ndyf = floorf(-dy);
    const int Kx = (int)ndxf, Ky = (int)ndyf;
    const float fx3 = -dx - ndxf, fy3 = -dy - ndyf;  // batch-uniform weights

    // --- bounds chain ---
    const int Xmin = (flip ? WW - 16 - ox : ox) + Kx;
    const int Ymin = oy + Ky;
    int XrLo, XrHi, YrLo, YrHi;
    rhull(Xmin, Xmin + 16, WW, XrLo, XrHi);
    rhull(Ymin, Ymin + 16, HH, YrLo, YrHi);

    const int Gx0 = (int)floorf(zw * ((float)XrLo - CX) + CX);       // monotone
    const int Gx1 = (int)floorf(zw * ((float)XrHi - CX) + CX) + 1;
    const int Gy0 = (int)floorf(zh * ((float)YrLo - CY) + CY);
    const int Gy1 = (int)floorf(zh * ((float)YrHi - CY) + CY) + 1;
    const int GH = min(Gy1 - Gy0 + 1, 22);

    int RgxLo, RgxHi, RgyLo, RgyHi;
    rhull(Gx0, Gx1, WW, RgxLo, RgxHi);
    rhull(Gy0, Gy1, HH, RgyLo, RgyHi);

    // rotated bbox of the reflected G rect (linear map -> corner extremes)
    const float rx0 = (float)RgxLo - CX, rx1 = (float)RgxHi - CX;
    const float ry0 = (float)RgyLo - CY, ry1 = (float)RgyHi - CY;
    const float xsmin = fminf(c * rx0, c * rx1) + fminf(-s * ry0, -s * ry1) + CX;
    const float xsmax = fmaxf(c * rx0, c * rx1) + fmaxf(-s * ry0, -s * ry1) + CX;
    const float ysmin = fminf(s * rx0, s * rx1) + fminf(c * ry0, c * ry1) + CY;
    const float ysmax = fmaxf(s * rx0, s * rx1) + fmaxf(c * ry0, c * ry1) + CY;
    int Cx0, Cx1, Cy0, Cy1;
    rhull((int)floorf(xsmin), (int)floorf(xsmax) + 1, WW, Cx0, Cx1);
    rhull((int)floorf(ysmin), (int)floorf(ysmax) + 1, HH, Cy0, Cy1);
    const int ColBase = min(Cx0, WW - 32);   // window [ColBase..+31] covers hull
    const int RowBase = min(Cy0, HH - 32);
    const int RowN = min(Cy1 - RowBase + 1, 32);

    // --- phase 0: stage original window, pre-scaled (always in-bounds) ---
    const float* img = image + (size_t)b * IMG_ELEMS;
    for (int id = threadIdx.x; id < 24 * RowN; id += 256) {
        const int r = id / 24, g = id - r * 24;      // 24 x f32x4 = 96dw/row
        const int src = ((RowBase + r) * WW + ColBase) * CC + g * 4;
        f32x4 v = *(const f32x4*)(img + src);
        v.x *= SCALE_K; v.y *= SCALE_K; v.z *= SCALE_K; v.w *= SCALE_K;
        *(f32x4*)(&SS[r * 100 + g * 4]) = v;
    }
    __syncthreads();

    // --- phase 1: rotate-stage values on the zoom tap grid ---
    for (int e = threadIdx.x; e < 22 * GH; e += 256) {
        const int gy = e / 22, gxi = e - gy * 22;    // gxi>=GW entries unused
        const int Rgx = reflect1(Gx0 + gxi, WW);
        const int Rgy = reflect1(Gy0 + gy, HH);
        const float xs = c * ((float)Rgx - CX) - s * ((float)Rgy - CY) + CX;
        const float ys = s * ((float)Rgx - CX) + c * ((float)Rgy - CY) + CY;
        const float xf = floorf(xs), yf = floorf(ys);
        const float fx = xs - xf, fy = ys - yf;
        const int x0 = (int)xf, y0 = (int)yf;
        const int c0 = min(max(reflect1(x0,     WW) - ColBase, 0), 31);
        const int c1 = min(max(reflect1(x0 + 1, WW) - ColBase, 0), 31);
        const int r0 = min(max(reflect1(y0,     HH) - RowBase, 0), 31);
        const int r1 = min(max(reflect1(y0 + 1, HH) - RowBase, 0), 31);
        const float* A  = &SS[r0 * 100 + c0 * 3];
        const float* Bv = &SS[r0 * 100 + c1 * 3];
        const float* Cv = &SS[r1 * 100 + c0 * 3];
        const float* Dv = &SS[r1 * 100 + c1 * 3];
        const float ofx = 1.0f - fx, ofy = 1.0f - fy;
        float* gp = &G[e * 3];
#pragma unroll
        for (int ch = 0; ch < CC; ++ch)
            gp[ch] = (A[ch] * ofx + Bv[ch] * fx) * ofy +
                     (Cv[ch] * ofx + Dv[ch] * fx) * fy;
    }
    __syncthreads();

    // --- phase 2: zoom-stage values on the 17x17 translate window ---
    for (int e = threadIdx.x; e < 289; e += 256) {
        const int ey = e / 17, ex = e - ey * 17;
        const int Xr = reflect1(Xmin + ex, WW);
        const int Yr = reflect1(Ymin + ey, HH);
        const float xs2 = zw * ((float)Xr - CX) + CX;  // exact reference expr
        const float ys2 = zh * ((float)Yr - CY) + CY;
        const float xf = floorf(xs2), yf = floorf(ys2);
        const float fx2 = xs2 - xf, fy2 = ys2 - yf;
        const int x20 = (int)xf, y20 = (int)yf;
        const int cA = min(max(x20     - Gx0, 0), 21);  // reflect lives in G
        const int cB = min(max(x20 + 1 - Gx0, 0), 21);
        const int rA = min(max(y20     - Gy0, 0), 21);
        const int rB = min(max(y20 + 1 - Gy0, 0), 21);
        const float* A  = &G[(rA * 22 + cA) * 3];
        const float* Bv = &G[(rA * 22 + cB) * 3];
        const float* Cv = &G[(rB * 22 + cA) * 3];
        const float* Dv = &G[(rB * 22 + cB) * 3];
        const float ofx = 1.0f - fx2, ofy = 1.0f - fy2;
        float* zp = &Z[e * 3];
#pragma unroll
        for (int ch = 0; ch < CC; ++ch)
            zp[ch] = (A[ch] * ofx + Bv[ch] * fx2) * ofy +
                     (Cv[ch] * ofx + Dv[ch] * fx2) * fy2;
    }
    __syncthreads();

    // --- phase 3: translate blend + flip, write output ---
    const int lx = threadIdx.x & 15, ly = threadIdx.x >> 4;
    const int ix = flip ? (15 - lx) : lx;
    const float* A  = &Z[(ly * 17 + ix) * 3];
    const float* Bv = &Z[(ly * 17 + ix + 1) * 3];
    const float* Cv = &Z[((ly + 1) * 17 + ix) * 3];
    const float* Dv = &Z[((ly + 1) * 17 + ix + 1) * 3];
    float* o = out + ((size_t)b * PIX + (size_t)(oy + ly) * WW + (ox + lx)) * CC;
    const float ofx = 1.0f - fx3, ofy = 1.0f - fy3;
#pragma unroll
    for (int ch = 0; ch < CC; ++ch)
        o[ch] = (A[ch] * ofx + Bv[ch] * fx3) * ofy +
                (Cv[ch] * ofx + Dv[ch] * fx3) * fy3;
}

extern "C" void kernel_launch(void* const* d_in, const int* in_sizes, int n_in,
                              void* d_out, int out_size, void* d_ws, size_t ws_size,
                              hipStream_t stream) {
    const float* image   = (const float*)d_in[0];
    const float* angle_u = (const float*)d_in[1];
    const float* zoom_u  = (const float*)d_in[2];
    const float* shift_u = (const float*)d_in[3];
    const float* flip_u  = (const float*)d_in[4];
    float* out = (float*)d_out;

    fused_kernel<<<NBLOCKS, 256, 0, stream>>>(image, out, angle_u, zoom_u,
                                              shift_u, flip_u);
}